// Round 3
// baseline (2140.829 us; speedup 1.0000x reference)
//
#include <hip/hip_runtime.h>
#include <hip/hip_bf16.h>

#define TT 4096   // B*S tokens
#define HD 1024   // hidden
#define ID 2816   // intermediate
#define ER 7      // routed experts

typedef short s16x8 __attribute__((ext_vector_type(8)));
typedef float f32x4 __attribute__((ext_vector_type(4)));

__device__ __forceinline__ uint32_t pkbf(float a, float b) {
    union { __hip_bfloat16 h[2]; uint32_t u; } z;
    z.h[0] = __float2bfloat16(a);
    z.h[1] = __float2bfloat16(b);
    return z.u;
}

// ---------------- router: 1 wave per token (fp32 in, fp32 out) ----------------
__global__ __launch_bounds__(64) void router_kernel(
    const float* __restrict__ x, const float* __restrict__ rw,
    const float* __restrict__ rbias, float* __restrict__ combine)
{
    const int t = blockIdx.x;
    const int lane = threadIdx.x;
    const float* xt = x + (size_t)t * HD;
    float acc[ER];
#pragma unroll
    for (int e = 0; e < ER; ++e) acc[e] = 0.f;
    for (int h = lane; h < HD; h += 64) {
        const float xv = xt[h];
#pragma unroll
        for (int e = 0; e < ER; ++e)
            acc[e] += xv * rw[h * ER + e];
    }
#pragma unroll
    for (int e = 0; e < ER; ++e) {
        float v = acc[e];
#pragma unroll
        for (int off = 32; off > 0; off >>= 1) v += __shfl_down(v, off, 64);
        acc[e] = v;
    }
    if (lane == 0) {
        float p[ER];
#pragma unroll
        for (int e = 0; e < ER; ++e) {
            const float lg = acc[e] + rbias[e];
            p[e] = 1.f / (1.f + __expf(-lg));
        }
        int i1 = 0;
#pragma unroll
        for (int e = 1; e < ER; ++e) if (p[e] > p[i1]) i1 = e;
        int i2 = (i1 == 0) ? 1 : 0;
#pragma unroll
        for (int e = 0; e < ER; ++e) {
            if (e == i1 || e == i2) continue;
            if (p[e] > p[i2]) i2 = e;
        }
        const float s = p[i1] + p[i2];
        float w[8];
#pragma unroll
        for (int e = 0; e < 8; ++e) w[e] = 0.f;
        w[i1] = p[i1] / s;
        w[i2] = p[i2] / s;
        w[7] = 1.f;   // shared-expert weight
        float* cb = combine + (size_t)t * 8;
#pragma unroll
        for (int e = 0; e < 8; ++e) cb[e] = w[e];
    }
}

// ---------------- tiled MFMA GEMM ----------------
// A: [M,K] row-major.  AF32=1 -> fp32 (converted to bf16 at staging); AF32=0 -> bf16.
// B: [K,N] fp32 row-major (converted to bf16 at staging, transposed in LDS).
// MODE 0: Hbuf[m,n] = bf16(silu(acc))
// MODE 1: Hbuf[m,n] = bf16(float(Hbuf[m,n]) * acc)
// MODE 2: Out[m,n] = beta*Out[m,n] + combine[m*8+wcol]*acc   (fp32, Out = d_out)
template <int MODE, int AF32>
__global__ __launch_bounds__(256) void gemm_kernel(
    const void* __restrict__ Av,
    const float* __restrict__ B,
    __hip_bfloat16* __restrict__ Hbuf,
    float* __restrict__ Out,
    const float* __restrict__ combine,
    int M, int N, int K, int wcol, int beta)
{
    // A tile: 128 rows x 32 k (bf16) -> row stride 20 dwords (16 data + 4 pad)
    // B tile: transposed to [n][k-pair dwords], same stride, XOR-swizzled 16B groups
    __shared__ uint32_t ldsA[128 * 20];
    __shared__ uint32_t ldsB[128 * 20];

    const int tid = threadIdx.x;
    const int n0 = blockIdx.x * 128;
    const int m0 = blockIdx.y * 128;

    const int lane = tid & 63;
    const int wave = tid >> 6;
    const int wm = (wave >> 1) * 64;
    const int wn = (wave & 1) * 64;
    const int r = lane & 15;
    const int quad = lane >> 4;

    f32x4 acc[4][4];
#pragma unroll
    for (int i = 0; i < 4; ++i)
#pragma unroll
        for (int j = 0; j < 4; ++j)
            acc[i][j] = (f32x4){0.f, 0.f, 0.f, 0.f};

    for (int kb = 0; kb < K; kb += 32) {
        // ---- stage A ----
        if (AF32) {
            const float* A = (const float*)Av;
            const int arow = tid >> 1;      // 0..127
            const int ah = tid & 1;         // k-half of 16
            const float* ap = A + (size_t)(m0 + arow) * K + kb + ah * 16;
            const float4 f0 = *(const float4*)ap;
            const float4 f1 = *(const float4*)(ap + 4);
            const float4 f2 = *(const float4*)(ap + 8);
            const float4 f3 = *(const float4*)(ap + 12);
            uint4 w0, w1;
            w0.x = pkbf(f0.x, f0.y); w0.y = pkbf(f0.z, f0.w);
            w0.z = pkbf(f1.x, f1.y); w0.w = pkbf(f1.z, f1.w);
            w1.x = pkbf(f2.x, f2.y); w1.y = pkbf(f2.z, f2.w);
            w1.z = pkbf(f3.x, f3.y); w1.w = pkbf(f3.z, f3.w);
            *(uint4*)&ldsA[arow * 20 + ah * 8] = w0;
            *(uint4*)&ldsA[arow * 20 + ah * 8 + 4] = w1;
        } else {
            const __hip_bfloat16* A = (const __hip_bfloat16*)Av;
            const int arow = tid >> 2;   // 0..63 (and +64)
            const int akc = tid & 3;     // 16B chunk within the 32-k row
            const uint4 v0 = *(const uint4*)(A + (size_t)(m0 + arow) * K + kb + akc * 8);
            const uint4 v1 = *(const uint4*)(A + (size_t)(m0 + arow + 64) * K + kb + akc * 8);
            *(uint4*)&ldsA[arow * 20 + akc * 4] = v0;
            *(uint4*)&ldsA[(arow + 64) * 20 + akc * 4] = v1;
        }
        // ---- stage B: fp32 -> bf16, transpose via k-pair packing ----
        {
            const int bkp = tid >> 4;   // 0..15 : k-pair index
            const int bnc = tid & 15;   // 0..15 : 8-wide n chunk
            const float* bp0 = B + (size_t)(kb + 2 * bkp) * N + n0 + bnc * 8;
            const float* bp1 = bp0 + N;
            const float4 a0 = *(const float4*)bp0;
            const float4 a1 = *(const float4*)(bp0 + 4);
            const float4 b0 = *(const float4*)bp1;
            const float4 b1 = *(const float4*)(bp1 + 4);
            const float r0[8] = {a0.x, a0.y, a0.z, a0.w, a1.x, a1.y, a1.z, a1.w};
            const float r1[8] = {b0.x, b0.y, b0.z, b0.w, b1.x, b1.y, b1.z, b1.w};
            const int grp = (((bkp >> 2) ^ (bnc & 3)) << 2);
            const int kk = bkp & 3;
#pragma unroll
            for (int j = 0; j < 8; ++j)
                ldsB[(bnc * 8 + j) * 20 + grp + kk] = pkbf(r0[j], r1[j]);
        }
        __syncthreads();

        s16x8 af[4], bfr[4];
#pragma unroll
        for (int mi = 0; mi < 4; ++mi) {
            const int row = wm + mi * 16 + r;
            af[mi] = *(const s16x8*)&ldsA[row * 20 + quad * 4];
        }
#pragma unroll
        for (int ni = 0; ni < 4; ++ni) {
            const int nl = wn + ni * 16 + r;
            const int g = ((quad ^ ((nl >> 3) & 3)) << 2);
            bfr[ni] = *(const s16x8*)&ldsB[nl * 20 + g];
        }
#pragma unroll
        for (int mi = 0; mi < 4; ++mi)
#pragma unroll
            for (int ni = 0; ni < 4; ++ni)
                acc[mi][ni] = __builtin_amdgcn_mfma_f32_16x16x32_bf16(
                    af[mi], bfr[ni], acc[mi][ni], 0, 0, 0);
        __syncthreads();
    }

    // ---- epilogue.  D layout: col = lane&15, row = quad*4 + reg ----
#pragma unroll
    for (int mi = 0; mi < 4; ++mi) {
#pragma unroll
        for (int i = 0; i < 4; ++i) {
            const int grow = m0 + wm + mi * 16 + quad * 4 + i;
#pragma unroll
            for (int ni = 0; ni < 4; ++ni) {
                const int gcol = n0 + wn + ni * 16 + r;
                const float v = acc[mi][ni][i];
                if (MODE == 0) {
                    const float sv = v / (1.f + __expf(-v));
                    Hbuf[(size_t)grow * N + gcol] = __float2bfloat16(sv);
                } else if (MODE == 1) {
                    const size_t idx = (size_t)grow * N + gcol;
                    const float hv = __bfloat162float(Hbuf[idx]);
                    Hbuf[idx] = __float2bfloat16(hv * v);
                } else {
                    const size_t idx = (size_t)grow * N + gcol;
                    const float w = combine[(size_t)grow * 8 + wcol];
                    const float prev = beta ? Out[idx] : 0.f;
                    Out[idx] = prev + w * v;
                }
            }
        }
    }
}

extern "C" void kernel_launch(void* const* d_in, const int* in_sizes, int n_in,
                              void* d_out, int out_size, void* d_ws, size_t ws_size,
                              hipStream_t stream)
{
    (void)in_sizes; (void)n_in; (void)out_size; (void)ws_size;
    const float* x  = (const float*)d_in[0];
    const float* rw = (const float*)d_in[1];
    const float* rb = (const float*)d_in[2];
    const float* sg = (const float*)d_in[3];
    const float* su = (const float*)d_in[4];
    const float* sd = (const float*)d_in[5];
    const float* rg = (const float*)d_in[6];
    const float* ru = (const float*)d_in[7];
    const float* rd = (const float*)d_in[8];
    float* out = (float*)d_out;   // reference output dtype = float32

    // workspace layout (~23.2 MB): combine[T*8] f32 | hbuf[T*I] bf16
    float* combine = (float*)d_ws;
    __hip_bfloat16* hbuf = (__hip_bfloat16*)(combine + (size_t)TT * 8);

    router_kernel<<<TT, 64, 0, stream>>>(x, rw, rb, combine);

    dim3 blk(256);
    dim3 gH(ID / 128, TT / 128);   // 22 x 32
    dim3 gD(HD / 128, TT / 128);   // 8  x 32

    for (int p = 0; p < 8; ++p) {
        const float *wg, *wu, *wd;
        if (p < ER) {
            wg = rg + (size_t)p * HD * ID;
            wu = ru + (size_t)p * HD * ID;
            wd = rd + (size_t)p * ID * HD;
        } else {
            wg = sg; wu = su; wd = sd;
        }
        gemm_kernel<0, 1><<<gH, blk, 0, stream>>>(x, wg, hbuf, nullptr, nullptr, TT, ID, HD, 0, 0);
        gemm_kernel<1, 1><<<gH, blk, 0, stream>>>(x, wu, hbuf, nullptr, nullptr, TT, ID, HD, 0, 0);
        gemm_kernel<2, 0><<<gD, blk, 0, stream>>>(hbuf, wd, nullptr, out, combine, TT, HD, ID, p, p == 0 ? 0 : 1);
    }
}

// Round 4
// 1643.999 us; speedup vs baseline: 1.3022x; 1.3022x over previous
//
#include <hip/hip_runtime.h>
#include <hip/hip_bf16.h>

#define TT 4096   // B*S tokens
#define HD 1024   // hidden
#define ID 2816   // intermediate
#define ER 7      // routed experts
#define HI (HD * ID)

typedef short s16x8 __attribute__((ext_vector_type(8)));
typedef float f32x4 __attribute__((ext_vector_type(4)));

__device__ __forceinline__ uint32_t pkbf(float a, float b) {
    union { __hip_bfloat16 h[2]; uint32_t u; } z;
    z.h[0] = __float2bfloat16(a);
    z.h[1] = __float2bfloat16(b);
    return z.u;
}

__device__ __forceinline__ void gl_lds16(const void* g, void* l) {
    __builtin_amdgcn_global_load_lds(
        (const __attribute__((address_space(1))) uint32_t*)g,
        (__attribute__((address_space(3))) uint32_t*)l, 16, 0, 0);
}

// ---------------- router: 1 wave per token (fp32 in, fp32 out) ----------------
__global__ __launch_bounds__(64) void router_kernel(
    const float* __restrict__ x, const float* __restrict__ rw,
    const float* __restrict__ rbias, float* __restrict__ combine)
{
    const int t = blockIdx.x;
    const int lane = threadIdx.x;
    const float* xt = x + (size_t)t * HD;
    float acc[ER];
#pragma unroll
    for (int e = 0; e < ER; ++e) acc[e] = 0.f;
    for (int h = lane; h < HD; h += 64) {
        const float xv = xt[h];
#pragma unroll
        for (int e = 0; e < ER; ++e)
            acc[e] += xv * rw[h * ER + e];
    }
#pragma unroll
    for (int e = 0; e < ER; ++e) {
        float v = acc[e];
#pragma unroll
        for (int off = 32; off > 0; off >>= 1) v += __shfl_down(v, off, 64);
        acc[e] = v;
    }
    if (lane == 0) {
        float p[ER];
#pragma unroll
        for (int e = 0; e < ER; ++e) {
            const float lg = acc[e] + rbias[e];
            p[e] = 1.f / (1.f + __expf(-lg));
        }
        int i1 = 0;
#pragma unroll
        for (int e = 1; e < ER; ++e) if (p[e] > p[i1]) i1 = e;
        int i2 = (i1 == 0) ? 1 : 0;
#pragma unroll
        for (int e = 0; e < ER; ++e) {
            if (e == i1 || e == i2) continue;
            if (p[e] > p[i2]) i2 = e;
        }
        const float s = p[i1] + p[i2];
        float w[8];
#pragma unroll
        for (int e = 0; e < 8; ++e) w[e] = 0.f;
        w[i1] = p[i1] / s;
        w[i2] = p[i2] / s;
        w[7] = 1.f;   // shared-expert weight
        float* cb = combine + (size_t)t * 8;
#pragma unroll
        for (int e = 0; e < 8; ++e) cb[e] = w[e];
    }
}

// ---------------- transpose+convert: fp32 [K][N] -> bf16 [N][K], 8 matrices ----
__global__ __launch_bounds__(256) void txp_kernel(
    const float* __restrict__ Wsh, const float* __restrict__ Wrt,
    __hip_bfloat16* __restrict__ dst, int K, int N)
{
    __shared__ float lds[64 * 65];
    const int z = blockIdx.z;
    const float* src = (z < ER) ? (Wrt + (size_t)z * HI) : Wsh;
    __hip_bfloat16* out = dst + (size_t)z * HI;
    const int n0 = blockIdx.x * 64, k0 = blockIdx.y * 64;
    const int t = threadIdx.x;
    const int r = t >> 4, c = (t & 15) * 4;
#pragma unroll
    for (int i = 0; i < 4; ++i) {
        const float4 v = *(const float4*)(src + (size_t)(k0 + r + 16 * i) * N + n0 + c);
        float* p = &lds[(r + 16 * i) * 65 + c];
        p[0] = v.x; p[1] = v.y; p[2] = v.z; p[3] = v.w;
    }
    __syncthreads();
    const int nr = t >> 3, kc = (t & 7) * 8;
#pragma unroll
    for (int i = 0; i < 2; ++i) {
        const int nn = nr + 32 * i;
        uint32_t w[4];
#pragma unroll
        for (int j = 0; j < 4; ++j)
            w[j] = pkbf(lds[(kc + 2 * j) * 65 + nn], lds[(kc + 2 * j + 1) * 65 + nn]);
        *(uint4*)(out + (size_t)(n0 + nn) * K + k0 + kc) = *(uint4*)w;
    }
}

// ---------------- fp32 -> bf16 straight convert (x) ----------------
__global__ __launch_bounds__(256) void cvt_kernel(
    const float* __restrict__ a, __hip_bfloat16* __restrict__ o)
{
    const size_t i = ((size_t)blockIdx.x * 256 + threadIdx.x) * 8;
    const float4 v0 = *(const float4*)(a + i);
    const float4 v1 = *(const float4*)(a + i + 4);
    uint32_t w[4] = { pkbf(v0.x, v0.y), pkbf(v0.z, v0.w),
                      pkbf(v1.x, v1.y), pkbf(v1.z, v1.w) };
    *(uint4*)(o + i) = *(uint4*)w;
}

__global__ __launch_bounds__(256) void zero_kernel(float* __restrict__ o)
{
    const size_t i = ((size_t)blockIdx.x * 256 + threadIdx.x) * 4;
    *(float4*)(o + i) = float4{0.f, 0.f, 0.f, 0.f};
}

// ---------------- fused gate+up GEMM (m97-style staging) ----------------
// X [TT][HD] bf16, Bg/Bu [ID][HD] bf16 (W^T), H [TT][ID] bf16
__global__ __launch_bounds__(256) void gu_kernel(
    const __hip_bfloat16* __restrict__ X,
    const __hip_bfloat16* __restrict__ Bg,
    const __hip_bfloat16* __restrict__ Bu,
    __hip_bfloat16* __restrict__ H)
{
    __shared__ __hip_bfloat16 sA[128 * 32];
    __shared__ __hip_bfloat16 sG[128 * 32];
    __shared__ __hip_bfloat16 sU[128 * 32];
    const int tid = threadIdx.x;
    const int n0 = blockIdx.x * 128;
    const int m0 = blockIdx.y * 128;
    const int lane = tid & 63, wave = tid >> 6;
    const int wm = (wave >> 1) * 64, wn = (wave & 1) * 64;
    const int r = lane & 15, quad = lane >> 4;

    f32x4 ag[4][4], au[4][4];
#pragma unroll
    for (int i = 0; i < 4; ++i)
#pragma unroll
        for (int j = 0; j < 4; ++j) {
            ag[i][j] = (f32x4){0.f, 0.f, 0.f, 0.f};
            au[i][j] = (f32x4){0.f, 0.f, 0.f, 0.f};
        }

    const int srow = tid >> 2;
    const int sk = (tid & 3) * 8;
    const size_t aoff = (size_t)(m0 + srow) * HD + sk;
    const size_t boff = (size_t)(n0 + srow) * HD + sk;
    char* lA = (char*)sA + tid * 16;
    char* lG = (char*)sG + tid * 16;
    char* lU = (char*)sU + tid * 16;

    for (int kb = 0; kb < HD; kb += 32) {
        gl_lds16(X + aoff + kb, lA);
        gl_lds16(X + aoff + (size_t)64 * HD + kb, lA + 4096);
        gl_lds16(Bg + boff + kb, lG);
        gl_lds16(Bg + boff + (size_t)64 * HD + kb, lG + 4096);
        gl_lds16(Bu + boff + kb, lU);
        gl_lds16(Bu + boff + (size_t)64 * HD + kb, lU + 4096);
        __syncthreads();

        s16x8 af[4], bg[4], bu[4];
#pragma unroll
        for (int mi = 0; mi < 4; ++mi)
            af[mi] = *(const s16x8*)&sA[(wm + mi * 16 + r) * 32 + quad * 8];
#pragma unroll
        for (int ni = 0; ni < 4; ++ni) {
            bg[ni] = *(const s16x8*)&sG[(wn + ni * 16 + r) * 32 + quad * 8];
            bu[ni] = *(const s16x8*)&sU[(wn + ni * 16 + r) * 32 + quad * 8];
        }
#pragma unroll
        for (int mi = 0; mi < 4; ++mi)
#pragma unroll
            for (int ni = 0; ni < 4; ++ni) {
                ag[mi][ni] = __builtin_amdgcn_mfma_f32_16x16x32_bf16(af[mi], bg[ni], ag[mi][ni], 0, 0, 0);
                au[mi][ni] = __builtin_amdgcn_mfma_f32_16x16x32_bf16(af[mi], bu[ni], au[mi][ni], 0, 0, 0);
            }
        __syncthreads();
    }

#pragma unroll
    for (int mi = 0; mi < 4; ++mi)
#pragma unroll
        for (int i = 0; i < 4; ++i) {
            const int grow = m0 + wm + mi * 16 + quad * 4 + i;
#pragma unroll
            for (int ni = 0; ni < 4; ++ni) {
                const int gcol = n0 + wn + ni * 16 + r;
                const float g = ag[mi][ni][i];
                const float u = au[mi][ni][i];
                const float h = (g / (1.f + __expf(-g))) * u;
                H[(size_t)grow * ID + gcol] = __float2bfloat16(h);
            }
        }
}

// ---------------- down GEMM, split-K=2, atomic combine epilogue ----------------
// Hb [TT][ID] bf16, Bd [HD][ID] bf16 (W^T), Out [TT][HD] fp32
__global__ __launch_bounds__(256) void down_kernel(
    const __hip_bfloat16* __restrict__ Hb,
    const __hip_bfloat16* __restrict__ Bd,
    float* __restrict__ Out,
    const float* __restrict__ combine, int wcol)
{
    __shared__ __hip_bfloat16 sA[128 * 32];
    __shared__ __hip_bfloat16 sB[128 * 32];
    const int tid = threadIdx.x;
    const int n0 = blockIdx.x * 128;
    const int m0 = blockIdx.y * 128;
    const int kb0 = blockIdx.z * (ID / 2);
    const int lane = tid & 63, wave = tid >> 6;
    const int wm = (wave >> 1) * 64, wn = (wave & 1) * 64;
    const int r = lane & 15, quad = lane >> 4;

    f32x4 acc[4][4];
#pragma unroll
    for (int i = 0; i < 4; ++i)
#pragma unroll
        for (int j = 0; j < 4; ++j)
            acc[i][j] = (f32x4){0.f, 0.f, 0.f, 0.f};

    const int srow = tid >> 2;
    const int sk = (tid & 3) * 8;
    const size_t aoff = (size_t)(m0 + srow) * ID + sk;
    const size_t boff = (size_t)(n0 + srow) * ID + sk;
    char* lA = (char*)sA + tid * 16;
    char* lB = (char*)sB + tid * 16;

    for (int kb = kb0; kb < kb0 + ID / 2; kb += 32) {
        gl_lds16(Hb + aoff + kb, lA);
        gl_lds16(Hb + aoff + (size_t)64 * ID + kb, lA + 4096);
        gl_lds16(Bd + boff + kb, lB);
        gl_lds16(Bd + boff + (size_t)64 * ID + kb, lB + 4096);
        __syncthreads();

        s16x8 af[4], bf[4];
#pragma unroll
        for (int mi = 0; mi < 4; ++mi)
            af[mi] = *(const s16x8*)&sA[(wm + mi * 16 + r) * 32 + quad * 8];
#pragma unroll
        for (int ni = 0; ni < 4; ++ni)
            bf[ni] = *(const s16x8*)&sB[(wn + ni * 16 + r) * 32 + quad * 8];
#pragma unroll
        for (int mi = 0; mi < 4; ++mi)
#pragma unroll
            for (int ni = 0; ni < 4; ++ni)
                acc[mi][ni] = __builtin_amdgcn_mfma_f32_16x16x32_bf16(af[mi], bf[ni], acc[mi][ni], 0, 0, 0);
        __syncthreads();
    }

#pragma unroll
    for (int mi = 0; mi < 4; ++mi)
#pragma unroll
        for (int i = 0; i < 4; ++i) {
            const int grow = m0 + wm + mi * 16 + quad * 4 + i;
            const float w = combine[(size_t)grow * 8 + wcol];
#pragma unroll
            for (int ni = 0; ni < 4; ++ni) {
                const int gcol = n0 + wn + ni * 16 + r;
                atomicAdd(&Out[(size_t)grow * HD + gcol], w * acc[mi][ni][i]);
            }
        }
}

// ================= fallback path (round-3, validated) =================
template <int MODE, int AF32>
__global__ __launch_bounds__(256) void gemm_kernel(
    const void* __restrict__ Av, const float* __restrict__ B,
    __hip_bfloat16* __restrict__ Hbuf, float* __restrict__ Out,
    const float* __restrict__ combine, int M, int N, int K, int wcol, int beta)
{
    __shared__ uint32_t ldsA[128 * 20];
    __shared__ uint32_t ldsB[128 * 20];
    const int tid = threadIdx.x;
    const int n0 = blockIdx.x * 128;
    const int m0 = blockIdx.y * 128;
    const int lane = tid & 63, wave = tid >> 6;
    const int wm = (wave >> 1) * 64, wn = (wave & 1) * 64;
    const int r = lane & 15, quad = lane >> 4;
    f32x4 acc[4][4];
#pragma unroll
    for (int i = 0; i < 4; ++i)
#pragma unroll
        for (int j = 0; j < 4; ++j) acc[i][j] = (f32x4){0.f, 0.f, 0.f, 0.f};
    for (int kb = 0; kb < K; kb += 32) {
        if (AF32) {
            const float* A = (const float*)Av;
            const int arow = tid >> 1, ah = tid & 1;
            const float* ap = A + (size_t)(m0 + arow) * K + kb + ah * 16;
            const float4 f0 = *(const float4*)ap;
            const float4 f1 = *(const float4*)(ap + 4);
            const float4 f2 = *(const float4*)(ap + 8);
            const float4 f3 = *(const float4*)(ap + 12);
            uint4 w0, w1;
            w0.x = pkbf(f0.x, f0.y); w0.y = pkbf(f0.z, f0.w);
            w0.z = pkbf(f1.x, f1.y); w0.w = pkbf(f1.z, f1.w);
            w1.x = pkbf(f2.x, f2.y); w1.y = pkbf(f2.z, f2.w);
            w1.z = pkbf(f3.x, f3.y); w1.w = pkbf(f3.z, f3.w);
            *(uint4*)&ldsA[arow * 20 + ah * 8] = w0;
            *(uint4*)&ldsA[arow * 20 + ah * 8 + 4] = w1;
        } else {
            const __hip_bfloat16* A = (const __hip_bfloat16*)Av;
            const int arow = tid >> 2, akc = tid & 3;
            const uint4 v0 = *(const uint4*)(A + (size_t)(m0 + arow) * K + kb + akc * 8);
            const uint4 v1 = *(const uint4*)(A + (size_t)(m0 + arow + 64) * K + kb + akc * 8);
            *(uint4*)&ldsA[arow * 20 + akc * 4] = v0;
            *(uint4*)&ldsA[(arow + 64) * 20 + akc * 4] = v1;
        }
        {
            const int bkp = tid >> 4, bnc = tid & 15;
            const float* bp0 = B + (size_t)(kb + 2 * bkp) * N + n0 + bnc * 8;
            const float* bp1 = bp0 + N;
            const float4 a0 = *(const float4*)bp0;
            const float4 a1 = *(const float4*)(bp0 + 4);
            const float4 b0 = *(const float4*)bp1;
            const float4 b1 = *(const float4*)(bp1 + 4);
            const float r0[8] = {a0.x, a0.y, a0.z, a0.w, a1.x, a1.y, a1.z, a1.w};
            const float r1[8] = {b0.x, b0.y, b0.z, b0.w, b1.x, b1.y, b1.z, b1.w};
            const int grp = (((bkp >> 2) ^ (bnc & 3)) << 2);
            const int kk = bkp & 3;
#pragma unroll
            for (int j = 0; j < 8; ++j)
                ldsB[(bnc * 8 + j) * 20 + grp + kk] = pkbf(r0[j], r1[j]);
        }
        __syncthreads();
        s16x8 af[4], bfr[4];
#pragma unroll
        for (int mi = 0; mi < 4; ++mi)
            af[mi] = *(const s16x8*)&ldsA[(wm + mi * 16 + r) * 20 + quad * 4];
#pragma unroll
        for (int ni = 0; ni < 4; ++ni) {
            const int nl = wn + ni * 16 + r;
            bfr[ni] = *(const s16x8*)&ldsB[nl * 20 + ((quad ^ ((nl >> 3) & 3)) << 2)];
        }
#pragma unroll
        for (int mi = 0; mi < 4; ++mi)
#pragma unroll
            for (int ni = 0; ni < 4; ++ni)
                acc[mi][ni] = __builtin_amdgcn_mfma_f32_16x16x32_bf16(af[mi], bfr[ni], acc[mi][ni], 0, 0, 0);
        __syncthreads();
    }
#pragma unroll
    for (int mi = 0; mi < 4; ++mi)
#pragma unroll
        for (int i = 0; i < 4; ++i) {
            const int grow = m0 + wm + mi * 16 + quad * 4 + i;
#pragma unroll
            for (int ni = 0; ni < 4; ++ni) {
                const int gcol = n0 + wn + ni * 16 + r;
                const float v = acc[mi][ni][i];
                if (MODE == 0) {
                    Hbuf[(size_t)grow * N + gcol] = __float2bfloat16(v / (1.f + __expf(-v)));
                } else if (MODE == 1) {
                    const size_t idx = (size_t)grow * N + gcol;
                    Hbuf[idx] = __float2bfloat16(__bfloat162float(Hbuf[idx]) * v);
                } else {
                    const size_t idx = (size_t)grow * N + gcol;
                    const float w = combine[(size_t)grow * 8 + wcol];
                    Out[idx] = (beta ? Out[idx] : 0.f) + w * v;
                }
            }
        }
}

extern "C" void kernel_launch(void* const* d_in, const int* in_sizes, int n_in,
                              void* d_out, int out_size, void* d_ws, size_t ws_size,
                              hipStream_t stream)
{
    (void)in_sizes; (void)n_in; (void)out_size;
    const float* x  = (const float*)d_in[0];
    const float* rw = (const float*)d_in[1];
    const float* rb = (const float*)d_in[2];
    const float* sg = (const float*)d_in[3];
    const float* su = (const float*)d_in[4];
    const float* sd = (const float*)d_in[5];
    const float* rg = (const float*)d_in[6];
    const float* ru = (const float*)d_in[7];
    const float* rd = (const float*)d_in[8];
    float* out = (float*)d_out;

    // fast-path ws layout
    const size_t SZ_COMBINE = (size_t)TT * 8 * 4;        // 131072
    const size_t SZ_XB      = (size_t)TT * HD * 2;       // 8 MB
    const size_t SZ_HBUF    = (size_t)TT * ID * 2;       // 23 MB
    const size_t SZ_W       = (size_t)8 * HI * 2;        // 46 MB per set
    const size_t REQUIRED   = SZ_COMBINE + SZ_XB + SZ_HBUF + 3 * SZ_W;  // ~170 MB

    if (ws_size >= REQUIRED) {
        char* p = (char*)d_ws;
        float* combine = (float*)p;            p += SZ_COMBINE;
        __hip_bfloat16* xb   = (__hip_bfloat16*)p; p += SZ_XB;
        __hip_bfloat16* hbuf = (__hip_bfloat16*)p; p += SZ_HBUF;
        __hip_bfloat16* wtg  = (__hip_bfloat16*)p; p += SZ_W;
        __hip_bfloat16* wtu  = (__hip_bfloat16*)p; p += SZ_W;
        __hip_bfloat16* wtd  = (__hip_bfloat16*)p;

        zero_kernel<<<(TT * HD) / 1024, 256, 0, stream>>>(out);
        cvt_kernel<<<(TT * HD) / 2048, 256, 0, stream>>>(x, xb);
        txp_kernel<<<dim3(ID / 64, HD / 64, 8), 256, 0, stream>>>(sg, rg, wtg, HD, ID);
        txp_kernel<<<dim3(ID / 64, HD / 64, 8), 256, 0, stream>>>(su, ru, wtu, HD, ID);
        txp_kernel<<<dim3(HD / 64, ID / 64, 8), 256, 0, stream>>>(sd, rd, wtd, ID, HD);
        router_kernel<<<TT, 64, 0, stream>>>(x, rw, rb, combine);

        for (int e = 0; e < 8; ++e) {
            gu_kernel<<<dim3(ID / 128, TT / 128), 256, 0, stream>>>(
                xb, wtg + (size_t)e * HI, wtu + (size_t)e * HI, hbuf);
            down_kernel<<<dim3(HD / 128, TT / 128, 2), 256, 0, stream>>>(
                hbuf, wtd + (size_t)e * HI, out, combine, e);
        }
    } else {
        // fallback: round-3 validated path (~23.2 MB ws)
        float* combine = (float*)d_ws;
        __hip_bfloat16* hbuf = (__hip_bfloat16*)(combine + (size_t)TT * 8);
        router_kernel<<<TT, 64, 0, stream>>>(x, rw, rb, combine);
        dim3 blk(256);
        dim3 gH(ID / 128, TT / 128);
        dim3 gD(HD / 128, TT / 128);
        for (int p = 0; p < 8; ++p) {
            const float *wg, *wu, *wd;
            if (p < ER) {
                wg = rg + (size_t)p * HI;
                wu = ru + (size_t)p * HI;
                wd = rd + (size_t)p * HI;
            } else {
                wg = sg; wu = su; wd = sd;
            }
            gemm_kernel<0, 1><<<gH, blk, 0, stream>>>(x, wg, hbuf, nullptr, nullptr, TT, ID, HD, 0, 0);
            gemm_kernel<1, 1><<<gH, blk, 0, stream>>>(x, wu, hbuf, nullptr, nullptr, TT, ID, HD, 0, 0);
            gemm_kernel<2, 0><<<gD, blk, 0, stream>>>(hbuf, wd, nullptr, out, combine, TT, HD, ID, p, p == 0 ? 0 : 1);
        }
    }
}